// Round 22
// baseline (292.700 us; speedup 1.0000x reference)
//
#include <hip/hip_runtime.h>

// ---------------------------------------------------------------------------
// 2-layer GAT (PyG GATConv), MI355X.
// R22 (from R21 = 292.6us best):
//   B-fragment REGISTER DOUBLE-BUFFER in gemm_body. R21 evidence: gemm2 is
//   85% stall (MfmaUtil 7.3%, FETCH 13.8MB cache-resident) — every 32-k
//   iteration serially exposes B's L2 latency after the barrier. Occupancy
//   is grid-limited (~3 blk/CU, 800 blocks), so +32 VGPR for a second B set
//   costs nothing. Loop unrolled 2x, static buffer indices; B(k+32) and
//   A(k+32) fly under iteration k's MFMAs. Applied to both gemms.
//   Everything else frozen from R21.
// ---------------------------------------------------------------------------

typedef __attribute__((ext_vector_type(8))) short short8;
typedef __attribute__((ext_vector_type(4))) float f32x4;
typedef __attribute__((ext_vector_type(2))) float f32x2;

static __device__ __forceinline__ ushort f2bf(float f) {  // RNE
  uint u = __float_as_uint(f);
  return (ushort)((u + 0x7FFFu + ((u >> 16) & 1u)) >> 16);
}
static __device__ __forceinline__ float bf2f(ushort s) {
  return __uint_as_float(((uint)s) << 16);
}
static __device__ __forceinline__ unsigned char f2fp8(float f) {  // e4m3 (HW)
  int p = __builtin_amdgcn_cvt_pk_fp8_f32(f, f, 0, false);
  return (unsigned char)(p & 0xFF);
}
static __device__ __forceinline__ uint4 cvt8bf(const float4& a, const float4& b) {
  uint4 hh;
  hh.x = (uint)f2bf(a.x) | ((uint)f2bf(a.y) << 16);
  hh.y = (uint)f2bf(a.z) | ((uint)f2bf(a.w) << 16);
  hh.z = (uint)f2bf(b.x) | ((uint)f2bf(b.y) << 16);
  hh.w = (uint)f2bf(b.z) | ((uint)f2bf(b.w) << 16);
  return hh;
}

// ---------- fused weight-prep + dst histogram (+ per-edge slot pe) ---------
__global__ __launch_bounds__(256)
void k_prep_hist(const float* __restrict__ W1, const float* __restrict__ W2,
                 ushort* __restrict__ w1th, ushort* __restrict__ w1tl,
                 ushort* __restrict__ w2th, ushort* __restrict__ w2tl,
                 const int* __restrict__ dstv, int* __restrict__ cnt,
                 int* __restrict__ pe, int E) {
  const int b = blockIdx.x;
  if (b < 128) {  // W1 [128][256] -> [256][128] split
    int gid = b * 256 + threadIdx.x;
    int c = gid & 255, k = gid >> 8;
    float w = W1[(size_t)k * 256 + c];
    ushort h = f2bf(w);
    w1th[(size_t)c * 128 + k] = h;
    w1tl[(size_t)c * 128 + k] = f2bf(w - bf2f(h));
  } else if (b < 384) {  // W2 [256][256] -> [256][256] split
    int gid = (b - 128) * 256 + threadIdx.x;
    int c = gid & 255, k = gid >> 8;
    float w = W2[(size_t)k * 256 + c];
    ushort h = f2bf(w);
    w2th[(size_t)c * 256 + k] = h;
    w2tl[(size_t)c * 256 + k] = f2bf(w - bf2f(h));
  } else {  // histogram of dst; atomic return value = edge's slot
    int i = (b - 384) * 256 + threadIdx.x;
    if (i < E) pe[i] = atomicAdd(&cnt[dstv[i]], 1);
  }
}

// Single-pass exclusive scan with decoupled lookback (grid <= 256 blocks).
__global__ __launch_bounds__(256)
void k_scan(const int* __restrict__ cnt, int* __restrict__ rowptr,
            int* __restrict__ bsum, int* __restrict__ bflag, int N, int E) {
  __shared__ int sm[256];
  __shared__ int s_prev;
  const int b = blockIdx.x, tid = threadIdx.x;
  const int gid = b * 256 + tid;
  int v = (gid < N) ? cnt[gid] : 0;
  sm[tid] = v;
  __syncthreads();
  for (int off = 1; off < 256; off <<= 1) {
    int t = (tid >= off) ? sm[tid - off] : 0;
    __syncthreads();
    sm[tid] += t;
    __syncthreads();
  }
  if (tid == 255) {
    atomicExch(&bsum[b], sm[255]);
    __threadfence();
    atomicExch(&bflag[b], 1);
  }
  if (tid == 0) s_prev = 0;
  __syncthreads();
  if (tid < b) {
    while (atomicAdd(&bflag[tid], 0) == 0) {}
    atomicAdd(&s_prev, atomicAdd(&bsum[tid], 0));
  }
  __syncthreads();
  if (gid < N) rowptr[gid] = s_prev + sm[tid] - v;
  if (gid == 0) rowptr[N] = E;
}

// ----------------------------- MFMA GEMM body ------------------------------
// C[N,256] = A_bf16 @ (Bh+Bl)[K,256], Bt stored [256][K]. C -> FP8 e4m3.
// 2 MFMA terms. LDS holds A only (10.2 KB). B fragments from global with
// REGISTER DOUBLE-BUFFER (next k-tile's B flies under current MFMAs).
// FP32A=1: A fp32 -> bf16 at staging. FP32A=0: A already bf16.
// XCD-aligned swizzle: col-halves of a row block differ by 8 block ids.
template <int FP32A>
static __device__ __forceinline__
void gemm_body(int bid, const void* __restrict__ Aany,
               const ushort* __restrict__ Bth, const ushort* __restrict__ Btl,
               unsigned char* __restrict__ hout, int Nrows, int K,
               const float* __restrict__ att_s, const float* __restrict__ att_d,
               float* __restrict__ a_s, float* __restrict__ a_d) {
  __shared__ ushort As_h[128][40];

  const int nrb = (Nrows + 127) >> 7;
  const int rb = (bid >> 4) * 8 + (bid & 7);
  const int ch = (bid >> 3) & 1;
  if (rb >= nrb) return;
  const int row0 = rb * 128;
  const int col0 = ch * 128;

  const int t = threadIdx.x;
  const int lane = t & 63;
  const int w = t >> 6;
  const int wr = (w >> 1) * 64;
  const int wc = (w & 1) * 64;
  const int lrow = t >> 2;       // 0..63 staging row index
  const int kc = (t & 3) * 8;    // k-chunk within BK=32

  const float*  Af = (const float*)Aany;    // FP32A=1
  const ushort* Ah = (const ushort*)Aany;   // FP32A=0

  f32x4 acc[4][4] = {};

  float4 pf[2][2];
  uint4 pa_h[2];
  const uint4 z4 = make_uint4(0, 0, 0, 0);
#pragma unroll
  for (int p = 0; p < 2; p++) {
    int gr = row0 + p * 64 + lrow;
    if (FP32A) {
      if (gr < Nrows) {
        const float* ap = Af + (size_t)gr * K + kc;
        pf[p][0] = *(const float4*)(ap);
        pf[p][1] = *(const float4*)(ap + 4);
      } else {
        pf[p][0] = make_float4(0.f, 0.f, 0.f, 0.f);
        pf[p][1] = pf[p][0];
      }
    } else {
      if (gr < Nrows) pa_h[p] = *(const uint4*)(Ah + (size_t)gr * K + kc);
      else pa_h[p] = z4;
    }
  }

  const int fr = lane & 15;
  const int fq = lane >> 4;
  const ushort* bb_h = Bth + (size_t)(col0 + wc + fr) * K + fq * 8;
  const ushort* bb_l = Btl + (size_t)(col0 + wc + fr) * K + fq * 8;

  // B double-buffer: preload tile 0
  short8 fB_h[2][4], fB_l[2][4];
#pragma unroll
  for (int c = 0; c < 4; c++) {
    fB_h[0][c] = *(const short8*)(bb_h + (size_t)c * 16 * K);
    fB_l[0][c] = *(const short8*)(bb_l + (size_t)c * 16 * K);
  }

#define GEMM_STEP(CUR, NXT, K0)                                              \
  {                                                                          \
    _Pragma("unroll") for (int p = 0; p < 2; p++) {                          \
      uint4 hh;                                                              \
      if (FP32A) hh = cvt8bf(pf[p][0], pf[p][1]);                            \
      else hh = pa_h[p];                                                     \
      *(uint4*)(&As_h[p * 64 + lrow][kc]) = hh;                              \
    }                                                                        \
    __syncthreads();                                                         \
    if ((K0) + 32 < K) {                                                     \
      _Pragma("unroll") for (int p = 0; p < 2; p++) {                        \
        int gr = row0 + p * 64 + lrow;                                       \
        if (FP32A) {                                                         \
          if (gr < Nrows) {                                                  \
            const float* ap = Af + (size_t)gr * K + (K0) + 32 + kc;          \
            pf[p][0] = *(const float4*)(ap);                                 \
            pf[p][1] = *(const float4*)(ap + 4);                             \
          } else {                                                           \
            pf[p][0] = make_float4(0.f, 0.f, 0.f, 0.f);                      \
            pf[p][1] = pf[p][0];                                             \
          }                                                                  \
        } else {                                                             \
          if (gr < Nrows)                                                    \
            pa_h[p] = *(const uint4*)(Ah + (size_t)gr * K + (K0) + 32 + kc); \
          else pa_h[p] = z4;                                                 \
        }                                                                    \
      }                                                                      \
      _Pragma("unroll") for (int c = 0; c < 4; c++) {                        \
        fB_h[NXT][c] = *(const short8*)(bb_h + (size_t)c * 16 * K + (K0) + 32); \
        fB_l[NXT][c] = *(const short8*)(bb_l + (size_t)c * 16 * K + (K0) + 32); \
      }                                                                      \
    }                                                                        \
    short8 fa[4];                                                            \
    _Pragma("unroll") for (int r = 0; r < 4; r++)                            \
      fa[r] = *(const short8*)(&As_h[wr + r * 16 + fr][fq * 8]);             \
    _Pragma("unroll") for (int r = 0; r < 4; r++)                            \
      _Pragma("unroll") for (int c = 0; c < 4; c++) {                        \
        acc[r][c] = __builtin_amdgcn_mfma_f32_16x16x32_bf16(fa[r], fB_h[CUR][c], acc[r][c], 0, 0, 0); \
        acc[r][c] = __builtin_amdgcn_mfma_f32_16x16x32_bf16(fa[r], fB_l[CUR][c], acc[r][c], 0, 0, 0); \
      }                                                                      \
    __syncthreads();                                                         \
  }

  for (int k0 = 0; k0 < K; k0 += 64) {
    GEMM_STEP(0, 1, k0)
    GEMM_STEP(1, 0, k0 + 32)
  }
#undef GEMM_STEP

  // ---- C write (fp8 e4m3; L2 absorbs the 1B scatter)
#pragma unroll
  for (int r = 0; r < 4; r++)
#pragma unroll
    for (int c = 0; c < 4; c++) {
      int colg = col0 + wc + c * 16 + fr;
#pragma unroll
      for (int reg = 0; reg < 4; reg++) {
        int gr = row0 + wr + r * 16 + fq * 4 + reg;
        if (gr < Nrows)
          hout[(size_t)gr * 256 + colg] = f2fp8(acc[r][c][reg]);
      }
    }

  // ---- attention scores: wave's 64 cols = one head (wc 64-aligned)
  const int head = (col0 + wc) >> 6;
  float asv[4], adv[4];
#pragma unroll
  for (int c = 0; c < 4; c++) {
    asv[c] = att_s[col0 + wc + c * 16 + fr];
    adv[c] = att_d[col0 + wc + c * 16 + fr];
  }
#pragma unroll
  for (int r = 0; r < 4; r++)
#pragma unroll
    for (int reg = 0; reg < 4; reg++) {
      float ps = 0.f, pd = 0.f;
#pragma unroll
      for (int c = 0; c < 4; c++) {
        ps += acc[r][c][reg] * asv[c];
        pd += acc[r][c][reg] * adv[c];
      }
      ps += __shfl_xor(ps, 1); pd += __shfl_xor(pd, 1);
      ps += __shfl_xor(ps, 2); pd += __shfl_xor(pd, 2);
      ps += __shfl_xor(ps, 4); pd += __shfl_xor(pd, 4);
      ps += __shfl_xor(ps, 8); pd += __shfl_xor(pd, 8);
      if (fr == 0) {
        int gr = row0 + wr + r * 16 + fq * 4 + reg;
        if (gr < Nrows) {
          a_s[(size_t)gr * 4 + head] = ps;
          a_d[(size_t)gr * 4 + head] = pd;
        }
      }
    }
}

// ---- fused: gemm1 blocks first, NON-ATOMIC scatter blocks backfill --------
// Scatter: 4 edges/thread (1024/block) for ILP.
__global__ __launch_bounds__(256)
void k_gemm1_scatter(const float* __restrict__ x,
                     const ushort* __restrict__ Bth,
                     const ushort* __restrict__ Btl,
                     unsigned char* __restrict__ hout, int Nrows,
                     const float* __restrict__ att_s,
                     const float* __restrict__ att_d,
                     float* __restrict__ a_s, float* __restrict__ a_d,
                     const int* __restrict__ srcv, const int* __restrict__ dstv,
                     const int* __restrict__ rowptr, const int* __restrict__ pe,
                     int* __restrict__ col, int E, int gemm_blocks) {
  if ((int)blockIdx.x < gemm_blocks) {
    gemm_body<1>(blockIdx.x, x, Bth, Btl, hout, Nrows, 128,
                 att_s, att_d, a_s, a_d);
  } else {
    int base = ((int)blockIdx.x - gemm_blocks) * 1024 + threadIdx.x;
#pragma unroll
    for (int k = 0; k < 4; k++) {
      int i = base + k * 256;
      if (i < E) col[rowptr[dstv[i]] + pe[i]] = srcv[i];
    }
  }
}

__global__ __launch_bounds__(256)
void k_gemm2(const ushort* __restrict__ Ah,
             const ushort* __restrict__ Bth, const ushort* __restrict__ Btl,
             unsigned char* __restrict__ hout, int Nrows,
             const float* __restrict__ att_s, const float* __restrict__ att_d,
             float* __restrict__ a_s, float* __restrict__ a_d) {
  gemm_body<0>(blockIdx.x, Ah, Bth, Btl, hout, Nrows, 256,
               att_s, att_d, a_s, a_d);
}

// ----------------------------- aggregation ---------------------------------
// ONE wave per node; lane owns channels [4*lane, 4*lane+3], head = lane>>4.
// h is FP8 e4m3 for BOTH layers: 4 B/lane gather (256 B/edge), HW cvt decode.
// LAYER 1: relu(acc/den + bias) -> plain bf16.
// LAYER 2: fused finale — head-mean + bias + relu + softmax(64) -> outp.
template <int LAYER>
__global__ __launch_bounds__(256)
void k_aggr(const unsigned char* __restrict__ hsrc,
            const int* __restrict__ rowptr, const int* __restrict__ col,
            const float* __restrict__ a_s, const float* __restrict__ a_d,
            const float* __restrict__ bias,
            ushort* __restrict__ out_h, float* __restrict__ outp, int N) {
  __shared__ int   s_sh[4][64];
  __shared__ float w_sh[4][256];
  const int wv = threadIdx.x >> 6;
  const int lane = threadIdx.x & 63;
  const int node = blockIdx.x * 4 + wv;
  if (node >= N) return;
  const int hd = lane >> 4;
  const int beg = rowptr[node], end = rowptr[node + 1];
  const float4 adst = *(const float4*)(a_d + (size_t)node * 4);

  float4 acc = make_float4(0.f, 0.f, 0.f, 0.f);
  float wsum = 0.f;
  const char* hbase = (const char*)hsrc + lane * 4;  // 256 B row stride

  for (int c0 = beg; c0 < end; c0 += 64) {
    int nc = min(64, end - c0);
    int s = 0;
    float4 w4 = make_float4(0.f, 0.f, 0.f, 0.f);
    if (lane < nc) {
      s = col[c0 + lane];
      float4 a = *(const float4*)(a_s + (size_t)s * 4);
      float e0 = a.x + adst.x; e0 = e0 > 0.f ? e0 : 0.2f * e0;
      float e1 = a.y + adst.y; e1 = e1 > 0.f ? e1 : 0.2f * e1;
      float e2 = a.z + adst.z; e2 = e2 > 0.f ? e2 : 0.2f * e2;
      float e3 = a.w + adst.w; e3 = e3 > 0.f ? e3 : 0.2f * e3;
      w4 = make_float4(__expf(e0), __expf(e1), __expf(e2), __expf(e3));
    }
    s_sh[wv][lane] = s;
    *(float4*)(&w_sh[wv][lane * 4]) = w4;
    asm volatile("s_waitcnt lgkmcnt(0)" ::: "memory");

    const float* wrow = &w_sh[wv][hd];
    const int*   srow = &s_sh[wv][0];
    int j = 0;
    for (; j + 4 <= nc; j += 4) {
      int sj0 = srow[j], sj1 = srow[j + 1], sj2 = srow[j + 2], sj3 = srow[j + 3];
      float w0 = wrow[4 * j],      w1 = wrow[4 * j + 4];
      float w2 = wrow[4 * j + 8],  w3 = wrow[4 * j + 12];
      uint p0 = *(const uint*)(hbase + ((size_t)((uint)sj0 << 8)));
      uint p1 = *(const uint*)(hbase + ((size_t)((uint)sj1 << 8)));
      uint p2 = *(const uint*)(hbase + ((size_t)((uint)sj2 << 8)));
      uint p3 = *(const uint*)(hbase + ((size_t)((uint)sj3 << 8)));
      f32x2 l0 = __builtin_amdgcn_cvt_pk_f32_fp8(p0, false);
      f32x2 h0 = __builtin_amdgcn_cvt_pk_f32_fp8(p0, true);
      f32x2 l1 = __builtin_amdgcn_cvt_pk_f32_fp8(p1, false);
      f32x2 h1 = __builtin_amdgcn_cvt_pk_f32_fp8(p1, true);
      f32x2 l2 = __builtin_amdgcn_cvt_pk_f32_fp8(p2, false);
      f32x2 h2 = __builtin_amdgcn_cvt_pk_f32_fp8(p2, true);
      f32x2 l3 = __builtin_amdgcn_cvt_pk_f32_fp8(p3, false);
      f32x2 h3 = __builtin_amdgcn_cvt_pk_f32_fp8(p3, true);
      wsum += w0 + w1 + w2 + w3;
      acc.x += w0 * l0.x; acc.y += w0 * l0.y; acc.z += w0 * h0.x; acc.w += w0 * h0.y;
      acc.x += w1 * l1.x; acc.y += w1 * l1.y; acc.z += w1 * h1.x; acc.w += w1 * h1.y;
      acc.x += w2 * l2.x; acc.y += w2 * l2.y; acc.z += w2 * h2.x; acc.w += w2 * h2.y;
      acc.x += w3 * l3.x; acc.y += w3 * l3.y; acc.z += w3 * h3.x; acc.w += w3 * h3.y;
    }
    for (; j < nc; j++) {
      int sj = srow[j];
      float ww = wrow[4 * j];
      uint p = *(const uint*)(hbase + ((size_t)((uint)sj << 8)));
      f32x2 lo = __builtin_amdgcn_cvt_pk_f32_fp8(p, false);
      f32x2 hi = __builtin_amdgcn_cvt_pk_f32_fp8(p, true);
      wsum += ww;
      acc.x += ww * lo.x; acc.y += ww * lo.y;
      acc.z += ww * hi.x; acc.w += ww * hi.y;
    }
  }

  float inv = 1.0f / wsum;  // deg>=1 via self-loop
  float4 v = make_float4(acc.x * inv, acc.y * inv, acc.z * inv, acc.w * inv);

  if (LAYER == 1) {
    const float4 bv = *(const float4*)(bias + lane * 4);
    v.x = fmaxf(v.x + bv.x, 0.f);
    v.y = fmaxf(v.y + bv.y, 0.f);
    v.z = fmaxf(v.z + bv.z, 0.f);
    v.w = fmaxf(v.w + bv.w, 0.f);
    ushort4 h;
    h.x = f2bf(v.x); h.y = f2bf(v.y); h.z = f2bf(v.z); h.w = f2bf(v.w);
    *(ushort4*)(out_h + (size_t)node * 256 + lane * 4) = h;
  } else {
    // fused finale: head-mean + bias + relu + softmax(64)
    v.x += __shfl_xor(v.x, 16); v.y += __shfl_xor(v.y, 16);
    v.z += __shfl_xor(v.z, 16); v.w += __shfl_xor(v.w, 16);
    v.x += __shfl_xor(v.x, 32); v.y += __shfl_xor(v.y, 32);
    v.z += __shfl_xor(v.z, 32); v.w += __shfl_xor(v.w, 32);
    const int c4 = (lane & 15) * 4;
    const float4 bv = *(const float4*)(bias + c4);
    v.x = fmaxf(v.x * 0.25f + bv.x, 0.f);
    v.y = fmaxf(v.y * 0.25f + bv.y, 0.f);
    v.z = fmaxf(v.z * 0.25f + bv.z, 0.f);
    v.w = fmaxf(v.w * 0.25f + bv.w, 0.f);
    float mx = fmaxf(fmaxf(v.x, v.y), fmaxf(v.z, v.w));
    for (int off = 8; off >= 1; off >>= 1) mx = fmaxf(mx, __shfl_xor(mx, off));
    v.x = __expf(v.x - mx); v.y = __expf(v.y - mx);
    v.z = __expf(v.z - mx); v.w = __expf(v.w - mx);
    float sum = v.x + v.y + v.z + v.w;
    for (int off = 8; off >= 1; off >>= 1) sum += __shfl_xor(sum, off);
    float is = 1.0f / sum;
    v.x *= is; v.y *= is; v.z *= is; v.w *= is;
    if (lane < 16) *(float4*)(outp + (size_t)node * 64 + c4) = v;
  }
}

// ---------------------------------------------------------------------------

extern "C" void kernel_launch(void* const* d_in, const int* in_sizes, int n_in,
                              void* d_out, int out_size, void* d_ws, size_t ws_size,
                              hipStream_t stream) {
  const float* x   = (const float*)d_in[0];
  const int*   ei  = (const int*)d_in[1];
  const float* W1  = (const float*)d_in[2];
  const float* as1 = (const float*)d_in[3];
  const float* ad1 = (const float*)d_in[4];
  const float* b1  = (const float*)d_in[5];
  const float* W2  = (const float*)d_in[6];
  const float* as2 = (const float*)d_in[7];
  const float* ad2 = (const float*)d_in[8];
  const float* b2  = (const float*)d_in[9];
  float* out = (float*)d_out;

  const int N = in_sizes[0] / 128;
  const int E = in_sizes[1] / 2;
  const int* srcv = ei;
  const int* dstv = ei + E;

  // ---- workspace layout
  unsigned char* h8 = (unsigned char*)d_ws;       // [N,256] fp8 (both layers)
  ushort* hb   = (ushort*)(h8 + (size_t)N * 256); // [N,256] bf16 (aggr1 out)
  ushort* w1th = hb + (size_t)N * 256;            // [256][128] x2
  ushort* w1tl = w1th + 256 * 128;
  ushort* w2th = w1tl + 256 * 128;                // [256][256] x2
  ushort* w2tl = w2th + 256 * 256;
  float*  zbuf = (float*)(w2tl + 256 * 256);      // a_s1,a_d1,a_s2,a_d2 [16N]
  float* a_s1 = zbuf;
  float* a_d1 = a_s1 + (size_t)N * 4;
  float* a_s2 = a_d1 + (size_t)N * 4;
  float* a_d2 = a_s2 + (size_t)N * 4;
  int* rowptr = (int*)(zbuf + (size_t)N * 16);    // [N+1] (+pad)
  int* cnt    = rowptr + (N + 4);                 // [N]      (memset region)
  int* bflag  = cnt + N;                          // [256]    (memset region)
  int* bsum   = bflag + 256;                      // [256]
  int* pe     = bsum + 256;                       // [E]  per-edge slot
  int* colx   = pe + E;                           // [E]

  const int nb = (N + 255) / 256;  // <=256 required by k_scan lookback
  const int eb = (E + 255) / 256;
  const int eb4 = (E + 1023) / 1024;  // 4 edges/thread scatter blocks

  // XCD-aligned swizzled 1-D grid: 16 blocks per group of 8 row blocks
  const int nrb = (N + 127) / 128;
  const int gemm_blocks = ((nrb + 7) / 8) * 16;
  const int wb = (N + 3) / 4;  // one wave per node

  hipMemsetAsync(cnt, 0, ((size_t)N + 256) * 4, stream);  // cnt + bflag
  k_prep_hist<<<384 + eb, 256, 0, stream>>>(W1, W2, w1th, w1tl, w2th, w2tl,
                                            dstv, cnt, pe, E);
  k_scan<<<nb, 256, 0, stream>>>(cnt, rowptr, bsum, bflag, N, E);
  k_gemm1_scatter<<<gemm_blocks + eb4, 256, 0, stream>>>(
      x, w1th, w1tl, h8, N, as1, ad1, a_s1, a_d1,
      srcv, dstv, rowptr, pe, colx, E, gemm_blocks);
  k_aggr<1><<<wb, 256, 0, stream>>>(h8, rowptr, colx, a_s1, a_d1, b1,
                                    hb, nullptr, N);
  k_gemm2<<<gemm_blocks, 256, 0, stream>>>(hb, w2th, w2tl, h8, N,
                                           as2, ad2, a_s2, a_d2);
  k_aggr<2><<<wb, 256, 0, stream>>>(h8, rowptr, colx, a_s2, a_d2, b2,
                                    nullptr, out, N);
}